// Round 7
// baseline (1297.753 us; speedup 1.0000x reference)
//
#include <hip/hip_runtime.h>
#include <cstdint>
#include <cstddef>

typedef unsigned short ushort_t;
typedef short bf16x8 __attribute__((ext_vector_type(8)));
typedef float f32x4 __attribute__((ext_vector_type(4)));

__device__ __forceinline__ float bf2f(ushort_t h) {
  union { unsigned u; float f; } v; v.u = ((unsigned)h) << 16; return v.f;
}
__device__ __forceinline__ ushort_t f2bf(float f) {
  union { float f; unsigned u; } v; v.f = f;
  unsigned u = v.u;
  return (ushort_t)((u + 0x7fffu + ((u >> 16) & 1u)) >> 16);
}

// async 16B/lane global->LDS DMA (wave-uniform LDS base, per-lane global src)
#define GLOAD16(g, l)                                                         \
  __builtin_amdgcn_global_load_lds(                                           \
      (const __attribute__((address_space(1))) void*)(g),                     \
      (__attribute__((address_space(3))) void*)(l), 16, 0, 0)

// ---------------------------------------------------------------------------
// Weight prep: (CO, C, KS2) f32 -> (CO, KS2, C) bf16   (tap-major K order)
// ---------------------------------------------------------------------------
__global__ __launch_bounds__(256) void wprep(const float* __restrict__ in,
                                             ushort_t* __restrict__ out,
                                             int CO, int C, int KS2) {
  int idx = blockIdx.x * 256 + threadIdx.x;
  int total = CO * C * KS2;
  if (idx >= total) return;
  int co  = idx / (C * KS2);
  int rem = idx - co * (C * KS2);
  int tap = rem / C;
  int c   = rem - tap * C;
  out[idx] = f2bf(in[(size_t)co * C * KS2 + (size_t)c * KS2 + tap]);
}

// ---------------------------------------------------------------------------
// f32 -> (hi bf16, lo bf16) split; rows >= rows_in are zero (N padding)
// ---------------------------------------------------------------------------
__global__ __launch_bounds__(256) void fsplit(const float* __restrict__ in,
                                              ushort_t* __restrict__ hi,
                                              ushort_t* __restrict__ lo,
                                              int rows_in, long long total) {
  long long idx = (long long)blockIdx.x * 256 + threadIdx.x;
  if (idx >= total) return;
  long long r = idx / 768;
  float x = (r < rows_in) ? in[idx] : 0.f;
  ushort_t h = f2bf(x);
  hi[idx] = h;
  lo[idx] = f2bf(x - bf2f(h));
}

// ---------------------------------------------------------------------------
// Zero the 1-px border of a padded NHWC buffer (ws is re-poisoned every call)
// ---------------------------------------------------------------------------
__global__ __launch_bounds__(256) void border_zero(ushort_t* __restrict__ buf,
                                                   int B, int PH, int PW, int C) {
  int nb = 2 * PW + 2 * (PH - 2);
  long long total = (long long)B * nb * C;
  long long idx = (long long)blockIdx.x * 256 + threadIdx.x;
  if (idx >= total) return;
  int c = (int)(idx % C);
  long long r = idx / C;
  int bp = (int)(r % nb);
  int b = (int)(r / nb);
  int y, x;
  if (bp < PW) { y = 0; x = bp; }
  else if (bp < 2 * PW) { y = PH - 1; x = bp - PW; }
  else { int e = bp - 2 * PW; y = 1 + (e >> 1); x = (e & 1) ? PW - 1 : 0; }
  buf[((size_t)(b * PH + y) * PW + x) * C + c] = 0;
}

// ---------------------------------------------------------------------------
// Upsample 2x bilinear (align_corners=False)
// up1: in f32 NCHW (16,512,24,24) -> out bf16 NHWC padded (16,50,50,512) interior
// ---------------------------------------------------------------------------
__global__ __launch_bounds__(256) void upsample1(const float* __restrict__ in,
                                                 ushort_t* __restrict__ out) {
  int idx = blockIdx.x * 256 + threadIdx.x;
  if (idx >= 16 * 48 * 48 * 512) return;
  int c = idx & 511;
  int px = idx >> 9;
  int x = px % 48; int rest = px / 48; int y = rest % 48; int b = rest / 48;
  int jy = y >> 1, jx = x >> 1;
  int y0, y1, x0, x1; float wy0, wy1, wx0, wx1;
  if (y & 1) { y0 = jy; y1 = (jy + 1 < 24) ? jy + 1 : 23; wy0 = 0.75f; wy1 = 0.25f; }
  else       { y0 = (jy > 0) ? jy - 1 : 0; y1 = jy; wy0 = 0.25f; wy1 = 0.75f; }
  if (x & 1) { x0 = jx; x1 = (jx + 1 < 24) ? jx + 1 : 23; wx0 = 0.75f; wx1 = 0.25f; }
  else       { x0 = (jx > 0) ? jx - 1 : 0; x1 = jx; wx0 = 0.25f; wx1 = 0.75f; }
  const float* p = in + ((size_t)b * 512 + c) * 576;
  float v = wy0 * (wx0 * p[y0 * 24 + x0] + wx1 * p[y0 * 24 + x1]) +
            wy1 * (wx0 * p[y1 * 24 + x0] + wx1 * p[y1 * 24 + x1]);
  out[(((size_t)b * 50 + y + 1) * 50 + (x + 1)) * 512 + c] = f2bf(v);
}

// up2: in bf16 NHWC (16,48,48,512) -> out bf16 NHWC padded (16,98,98,512) interior
__global__ __launch_bounds__(256) void upsample2(const ushort_t* __restrict__ in,
                                                 ushort_t* __restrict__ out) {
  int idx = blockIdx.x * 256 + threadIdx.x;
  if (idx >= 16 * 96 * 96 * 512) return;
  int c = idx & 511;
  int px = idx >> 9;
  int x = px % 96; int rest = px / 96; int y = rest % 96; int b = rest / 96;
  int jy = y >> 1, jx = x >> 1;
  int y0, y1, x0, x1; float wy0, wy1, wx0, wx1;
  if (y & 1) { y0 = jy; y1 = (jy + 1 < 48) ? jy + 1 : 47; wy0 = 0.75f; wy1 = 0.25f; }
  else       { y0 = (jy > 0) ? jy - 1 : 0; y1 = jy; wy0 = 0.25f; wy1 = 0.75f; }
  if (x & 1) { x0 = jx; x1 = (jx + 1 < 48) ? jx + 1 : 47; wx0 = 0.75f; wx1 = 0.25f; }
  else       { x0 = (jx > 0) ? jx - 1 : 0; x1 = jx; wx0 = 0.25f; wx1 = 0.75f; }
  const ushort_t* p = in + (size_t)b * 48 * 48 * 512 + c;
  float v = wy0 * (wx0 * bf2f(p[(y0 * 48 + x0) * 512]) + wx1 * bf2f(p[(y0 * 48 + x1) * 512])) +
            wy1 * (wx0 * bf2f(p[(y1 * 48 + x0) * 512]) + wx1 * bf2f(p[(y1 * 48 + x1) * 512]));
  out[(((size_t)b * 98 + y + 1) * 98 + (x + 1)) * 512 + c] = f2bf(v);
}

// ---------------------------------------------------------------------------
// Text GEMM via MFMA with hi/lo bf16 split (~f32 precision):
//   D = Ah.Bh + Ah.Bl + Al.Bh;  A = word (2048x768), B = txt_w (2432x768 pad)
// ---------------------------------------------------------------------------
__global__ __launch_bounds__(256, 2) void text_mfma(
    const ushort_t* __restrict__ wh, const ushort_t* __restrict__ wl,
    const ushort_t* __restrict__ th, const ushort_t* __restrict__ tl,
    const float* __restrict__ tb,
    ushort_t* __restrict__ wkbuf, float* __restrict__ dynbias) {
  __shared__ ushort_t Ahs[128 * 64];
  __shared__ ushort_t Als[128 * 64];
  __shared__ ushort_t Bhs[128 * 64];
  __shared__ ushort_t Bls[128 * 64];
  const int tid = threadIdx.x;
  const int lane = tid & 63;
  const int wid = tid >> 6;
  const int n0 = blockIdx.x * 128;
  const int m0 = blockIdx.y * 128;
  const int soff = ((lane & 7) ^ ((lane >> 3) & 7)) * 16;
  const int g8 = lane >> 3;
  const char *pah[4], *pal[4], *pbh[4], *pbl[4];
#pragma unroll
  for (int j = 0; j < 4; ++j) {
    int row = wid * 32 + j * 8 + g8;
    size_t ab = (size_t)(m0 + row) * 1536 + soff;
    pah[j] = (const char*)wh + ab;
    pal[j] = (const char*)wl + ab;
    size_t bb = (size_t)(n0 + row) * 1536 + soff;
    pbh[j] = (const char*)th + bb;
    pbl[j] = (const char*)tl + bb;
  }
  const int lr = lane & 15, hi4 = lane >> 4;
  const int cow = (wid >> 1) * 64;
  const int pxw = (wid & 1) * 64;
  int aoff[4], boff[4];
#pragma unroll
  for (int r = 0; r < 4; ++r) {
    int row = cow + r * 16 + lr;
    aoff[r] = row * 128 + ((hi4 ^ (row & 7)) * 16);
    row = pxw + r * 16 + lr;
    boff[r] = row * 128 + ((hi4 ^ (row & 7)) * 16);
  }
  f32x4 acc[4][4];
#pragma unroll
  for (int r = 0; r < 4; ++r)
#pragma unroll
    for (int q = 0; q < 4; ++q) acc[r][q] = (f32x4){0.f, 0.f, 0.f, 0.f};

#pragma unroll 1
  for (int k0 = 0; k0 < 768; k0 += 64) {
    const int kb = k0 * 2;
#pragma unroll
    for (int j = 0; j < 4; ++j) {
      const int ld = (wid * 4 + j) * 1024;
      GLOAD16(pah[j] + kb, (char*)Ahs + ld);
      GLOAD16(pal[j] + kb, (char*)Als + ld);
      GLOAD16(pbh[j] + kb, (char*)Bhs + ld);
      GLOAD16(pbl[j] + kb, (char*)Bls + ld);
    }
    __syncthreads();
#pragma unroll
    for (int ks = 0; ks < 2; ++ks) {
      const int kx = ks * 64;
      bf16x8 ah[4], al[4], bh[4], bl[4];
#pragma unroll
      for (int r = 0; r < 4; ++r) {
        ah[r] = *(const bf16x8*)((const char*)Ahs + (aoff[r] ^ kx));
        al[r] = *(const bf16x8*)((const char*)Als + (aoff[r] ^ kx));
        bh[r] = *(const bf16x8*)((const char*)Bhs + (boff[r] ^ kx));
        bl[r] = *(const bf16x8*)((const char*)Bls + (boff[r] ^ kx));
      }
#pragma unroll
      for (int r = 0; r < 4; ++r)
#pragma unroll
        for (int q = 0; q < 4; ++q)
          acc[r][q] = __builtin_amdgcn_mfma_f32_16x16x32_bf16(ah[r], bh[q], acc[r][q], 0, 0, 0);
#pragma unroll
      for (int r = 0; r < 4; ++r)
#pragma unroll
        for (int q = 0; q < 4; ++q)
          acc[r][q] = __builtin_amdgcn_mfma_f32_16x16x32_bf16(ah[r], bl[q], acc[r][q], 0, 0, 0);
#pragma unroll
      for (int r = 0; r < 4; ++r)
#pragma unroll
        for (int q = 0; q < 4; ++q)
          acc[r][q] = __builtin_amdgcn_mfma_f32_16x16x32_bf16(al[r], bh[q], acc[r][q], 0, 0, 0);
    }
    __syncthreads();
  }

#pragma unroll
  for (int r = 0; r < 4; ++r) {
#pragma unroll
    for (int q = 0; q < 4; ++q) {
      int n = n0 + pxw + q * 16 + lr;
      if (n > 2304) continue;
      float tbn = tb[n];
#pragma unroll
      for (int j = 0; j < 4; ++j) {
        int m = m0 + cow + r * 16 + hi4 * 4 + j;
        float v = acc[r][q][j] + tbn;
        if (n < 2304) {
          int c = n / 9, tap = n - c * 9;
          int nc = m >> 4, bb = m & 15;
          wkbuf[((size_t)bb * 128 + nc) * 2304 + tap * 256 + c] = f2bf(v);
        } else {
          dynbias[m] = v;
        }
      }
    }
  }
}

// ---------------------------------------------------------------------------
// 8-phase pipelined NHWC implicit-GEMM conv (KS=3, EPI=BN+ReLU->bf16 NHWC).
// BM=256 co x BN=256 px, BK=64, 512 thr / 8 waves (2M x 4N), wave 128x64.
// LDS 128KB = 2 chunk buffers x (A 32KB + B 32KB). Per chunk: 4 phases
// {stage 3/3/2/0 gloads for t+1 || ds_read quadrant || barrier || setprio+
//  16 MFMA || barrier}; single vmcnt(0) at chunk boundary (loads issued
// 2-4 phases earlier). Both-sides XOR swizzle as in conv_mfma.
// ---------------------------------------------------------------------------
template <int H, int W, int C, int MOUT>
__global__ __launch_bounds__(512, 2) void conv_mfma8(
    const ushort_t* __restrict__ in, const ushort_t* __restrict__ wt,
    const float* __restrict__ gg, const float* __restrict__ bb2,
    const float* __restrict__ mm, const float* __restrict__ vv,
    ushort_t* __restrict__ outb) {
  constexpr int PHI = H + 2, PWI = W + 2;
  constexpr int CC = C / 64;       // c0 chunks per tap
  constexpr int NT = 9 * CC;       // total K chunks
  __shared__ ushort_t lds[2 * 512 * 64];   // 128 KB

  const int tid = threadIdx.x;
  const int lane = tid & 63;
  const int wid = tid >> 6;
  const int p0t = blockIdx.x * 256;
  const int co0 = blockIdx.y * 256;
  const int b = blockIdx.z;

  // inverse swizzle on the global source; LDS dest lane-linear
  const int soff = ((tid & 7) ^ ((tid >> 3) & 7)) * 16;
  const int rowi = tid >> 3;  // 0..63

  const char* aptr[4];
#pragma unroll
  for (int j = 0; j < 4; ++j)
    aptr[j] = (const char*)wt + (size_t)(co0 + j * 64 + rowi) * ((size_t)9 * C * 2) + soff;
  const char* ibase = (const char*)in + (size_t)b * PHI * PWI * C * 2;
  const char* bptr[4];
#pragma unroll
  for (int i = 0; i < 4; ++i) {
    int p = p0t + i * 64 + rowi;
    int y = p / W, x = p % W;
    bptr[i] = ibase + (size_t)((y + 1) * PWI + (x + 1)) * C * 2 + soff;
  }

  const int lr = lane & 15, hi = lane >> 4;
  const int cow = (wid >> 2) * 128;  // 2 M-waves
  const int pxw = (wid & 3) * 64;    // 4 N-waves
  int aoff[8], boff[4];
#pragma unroll
  for (int r = 0; r < 8; ++r) {
    int row = cow + r * 16 + lr;
    aoff[r] = row * 128 + ((hi ^ (row & 7)) * 16);
  }
#pragma unroll
  for (int q = 0; q < 4; ++q) {
    int row = pxw + q * 16 + lr;
    boff[q] = 32768 + row * 128 + ((hi ^ (row & 7)) * 16);
  }

  f32x4 acc[8][4];
#pragma unroll
  for (int r = 0; r < 8; ++r)
#pragma unroll
    for (int q = 0; q < 4; ++q) acc[r][q] = (f32x4){0.f, 0.f, 0.f, 0.f};

  auto dec = [&](int t, int& ka, int& kb) {
    int tap = t / CC;
    int cb = (t - tap * CC) * 128;           // 64 channels in bytes
    ka = tap * C * 2 + cb;
    kb = ((tap / 3 - 1) * PWI + (tap % 3) - 1) * (C * 2) + cb;
  };

  // prologue: stage chunk 0 into buffer 0
  {
    int ka, kb; dec(0, ka, kb);
    char* lb = (char*)lds;
#pragma unroll
    for (int j = 0; j < 4; ++j) GLOAD16(aptr[j] + ka, lb + j * 8192 + wid * 1024);
#pragma unroll
    for (int i = 0; i < 4; ++i) GLOAD16(bptr[i] + kb, lb + 32768 + i * 8192 + wid * 1024);
  }
  asm volatile("s_waitcnt vmcnt(0)" ::: "memory");
  __builtin_amdgcn_s_barrier();

#pragma unroll 1
  for (int t = 0; t < NT; ++t) {
    const char* rb = (const char*)lds + (t & 1) * 65536;
    char* lb = (char*)lds + ((t & 1) ^ 1) * 65536;
    int ka = 0, kb = 0;
    const bool st = (t + 1) < NT;
    if (st) dec(t + 1, ka, kb);

    bf16x8 af[4], bfv[4];
    // ---- phase 0: ks0, r0-3; stage A0,A1,B0 ----
    if (st) {
      GLOAD16(aptr[0] + ka, lb + 0 * 8192 + wid * 1024);
      GLOAD16(aptr[1] + ka, lb + 1 * 8192 + wid * 1024);
      GLOAD16(bptr[0] + kb, lb + 32768 + 0 * 8192 + wid * 1024);
    }
#pragma unroll
    for (int q = 0; q < 4; ++q) bfv[q] = *(const bf16x8*)(rb + boff[q]);
#pragma unroll
    for (int r = 0; r < 4; ++r) af[r] = *(const bf16x8*)(rb + aoff[r]);
    __builtin_amdgcn_s_barrier();
    __builtin_amdgcn_s_setprio(1);
#pragma unroll
    for (int r = 0; r < 4; ++r)
#pragma unroll
      for (int q = 0; q < 4; ++q)
        acc[r][q] = __builtin_amdgcn_mfma_f32_16x16x32_bf16(af[r], bfv[q], acc[r][q], 0, 0, 0);
    __builtin_amdgcn_s_setprio(0);
    __builtin_amdgcn_s_barrier();
    // ---- phase 1: ks0, r4-7; stage A2,A3,B1 ----
    if (st) {
      GLOAD16(aptr[2] + ka, lb + 2 * 8192 + wid * 1024);
      GLOAD16(aptr[3] + ka, lb + 3 * 8192 + wid * 1024);
      GLOAD16(bptr[1] + kb, lb + 32768 + 1 * 8192 + wid * 1024);
    }
#pragma unroll
    for (int r = 0; r < 4; ++r) af[r] = *(const bf16x8*)(rb + aoff[r + 4]);
    __builtin_amdgcn_s_barrier();
    __builtin_amdgcn_s_setprio(1);
#pragma unroll
    for (int r = 0; r < 4; ++r)
#pragma unroll
      for (int q = 0; q < 4; ++q)
        acc[r + 4][q] = __builtin_amdgcn_mfma_f32_16x16x32_bf16(af[r], bfv[q], acc[r + 4][q], 0, 0, 0);
    __builtin_amdgcn_s_setprio(0);
    __builtin_amdgcn_s_barrier();
    // ---- phase 2: ks1, r0-3; stage B2,B3 ----
    if (st) {
      GLOAD16(bptr[2] + kb, lb + 32768 + 2 * 8192 + wid * 1024);
      GLOAD16(bptr[3] + kb, lb + 32768 + 3 * 8192 + wid * 1024);
    }
#pragma unroll
    for (int q = 0; q < 4; ++q) bfv[q] = *(const bf16x8*)(rb + (boff[q] ^ 64));
#pragma unroll
    for (int r = 0; r < 4; ++r) af[r] = *(const bf16x8*)(rb + (aoff[r] ^ 64));
    __builtin_amdgcn_s_barrier();
    __builtin_amdgcn_s_setprio(1);
#pragma unroll
    for (int r = 0; r < 4; ++r)
#pragma unroll
      for (int q = 0; q < 4; ++q)
        acc[r][q] = __builtin_amdgcn_mfma_f32_16x16x32_bf16(af[r], bfv[q], acc[r][q], 0, 0, 0);
    __builtin_amdgcn_s_setprio(0);
    __builtin_amdgcn_s_barrier();
    // ---- phase 3: ks1, r4-7; no stage; chunk-boundary vmcnt ----
#pragma unroll
    for (int r = 0; r < 4; ++r) af[r] = *(const bf16x8*)(rb + (aoff[r + 4] ^ 64));
    __builtin_amdgcn_s_barrier();
    __builtin_amdgcn_s_setprio(1);
#pragma unroll
    for (int r = 0; r < 4; ++r)
#pragma unroll
      for (int q = 0; q < 4; ++q)
        acc[r + 4][q] = __builtin_amdgcn_mfma_f32_16x16x32_bf16(af[r], bfv[q], acc[r + 4][q], 0, 0, 0);
    __builtin_amdgcn_s_setprio(0);
    asm volatile("s_waitcnt vmcnt(0)" ::: "memory");
    __builtin_amdgcn_s_barrier();
  }

  // epilogue: BN+ReLU -> bf16 NHWC (D col=pixel, row=co)
#pragma unroll
  for (int r = 0; r < 8; ++r) {
    const int co = co0 + cow + r * 16 + hi * 4;
    float sc[4], sh[4];
#pragma unroll
    for (int j = 0; j < 4; ++j) {
      float inv = gg[co + j] * rsqrtf(vv[co + j] + 1e-5f);
      sc[j] = inv; sh[j] = bb2[co + j] - mm[co + j] * inv;
    }
#pragma unroll
    for (int q = 0; q < 4; ++q) {
      int p = p0t + pxw + q * 16 + lr;
      int y = p / W, x = p % W;
      ushort_t pk[4];
#pragma unroll
      for (int j = 0; j < 4; ++j) {
        float v = fmaxf(acc[r][q][j] * sc[j] + sh[j], 0.f);
        pk[j] = f2bf(v);
      }
      *(uint2*)&outb[(((size_t)b * H + y) * W + x) * MOUT + co] = *(const uint2*)pk;
    }
  }
}

// ---------------------------------------------------------------------------
// 2-barrier NHWC implicit-GEMM conv (kept for conv3 / dynamic conv).
// ---------------------------------------------------------------------------
template <int KS, int EPI, int BM, int BN, int MW, int NW, int H, int W, int C,
          int MOUT, bool PIW, bool OPAD>
__global__ __launch_bounds__(256, 2) void conv_mfma(
    const ushort_t* __restrict__ in, const ushort_t* __restrict__ wt,
    const float* __restrict__ p0, const float* __restrict__ p1,
    const float* __restrict__ p2, const float* __restrict__ p3,
    ushort_t* __restrict__ outb, float* __restrict__ outf) {
  constexpr int WAVES = 4;
  constexpr int AINST = BM / (8 * WAVES);
  constexpr int BINST = BN / (8 * WAVES);
  constexpr int MR = BM / MW / 16;
  constexpr int NR = BN / NW / 16;
  constexpr int KK = KS * KS;
  constexpr int PHI = (KS == 3) ? H + 2 : H;
  constexpr int PWI = (KS == 3) ? W + 2 : W;
  __shared__ ushort_t Asm[BM * 64];
  __shared__ ushort_t Bsm[BN * 64];

  const int tid = threadIdx.x;
  const int lane = tid & 63;
  const int wid = tid >> 6;
  const int p0t = blockIdx.x * BN;
  const int co0 = blockIdx.y * BM;
  const int b = blockIdx.z;

  const int soff = ((lane & 7) ^ ((lane >> 3) & 7)) * 16;

  const char* wbase = (const char*)wt + (PIW ? (size_t)b * MOUT * KK * C * 2 : 0);
  const char* aptr[AINST];
#pragma unroll
  for (int j = 0; j < AINST; ++j) {
    int arow = wid * (AINST * 8) + j * 8 + (lane >> 3);
    aptr[j] = wbase + (size_t)(co0 + arow) * ((size_t)KK * C * 2) + soff;
  }
  const char* ibase = (const char*)in + (size_t)b * PHI * PWI * C * 2;
  const char* bptr[BINST];
#pragma unroll
  for (int i = 0; i < BINST; ++i) {
    int brow = wid * (BINST * 8) + i * 8 + (lane >> 3);
    int p = p0t + brow;
    int y = p / W, x = p % W;
    int off = (KS == 3) ? ((y + 1) * PWI + (x + 1)) : (y * W + x);
    bptr[i] = ibase + (size_t)off * C * 2 + soff;
  }

  const int lr = lane & 15, hi = lane >> 4;
  const int cow = (wid / NW) * (BM / MW);
  const int pxw = (wid % NW) * (BN / NW);
  int aoff[MR], boff[NR];
#pragma unroll
  for (int r = 0; r < MR; ++r) {
    int row = cow + r * 16 + lr;
    aoff[r] = row * 128 + ((hi ^ (row & 7)) * 16);
  }
#pragma unroll
  for (int q = 0; q < NR; ++q) {
    int row = pxw + q * 16 + lr;
    boff[q] = row * 128 + ((hi ^ (row & 7)) * 16);
  }

  f32x4 acc[MR][NR];
#pragma unroll
  for (int r = 0; r < MR; ++r)
#pragma unroll
    for (int q = 0; q < NR; ++q) acc[r][q] = (f32x4){0.f, 0.f, 0.f, 0.f};

#pragma unroll 1
  for (int tap = 0; tap < KK; ++tap) {
    const int toff = (KS == 3) ? ((tap / 3 - 1) * PWI + (tap % 3 - 1)) * C * 2 : 0;
#pragma unroll 1
    for (int c0 = 0; c0 < C; c0 += 64) {
      const int koff = (tap * C + c0) * 2;
#pragma unroll
      for (int j = 0; j < AINST; ++j)
        GLOAD16(aptr[j] + koff, (char*)Asm + (wid * AINST + j) * 1024);
#pragma unroll
      for (int i = 0; i < BINST; ++i)
        GLOAD16(bptr[i] + toff + c0 * 2, (char*)Bsm + (wid * BINST + i) * 1024);
      __syncthreads();
#pragma unroll
      for (int ks = 0; ks < 2; ++ks) {
        const int kx = ks * 64;
        bf16x8 af[MR], bfv[NR];
#pragma unroll
        for (int r = 0; r < MR; ++r)
          af[r] = *(const bf16x8*)((const char*)Asm + (aoff[r] ^ kx));
#pragma unroll
        for (int q = 0; q < NR; ++q)
          bfv[q] = *(const bf16x8*)((const char*)Bsm + (boff[q] ^ kx));
#pragma unroll
        for (int r = 0; r < MR; ++r)
#pragma unroll
          for (int q = 0; q < NR; ++q)
            acc[r][q] = __builtin_amdgcn_mfma_f32_16x16x32_bf16(af[r], bfv[q], acc[r][q], 0, 0, 0);
      }
      __syncthreads();
    }
  }

#pragma unroll
  for (int r = 0; r < MR; ++r) {
    const int co = co0 + cow + r * 16 + hi * 4;
    float sc[4], sh[4];
#pragma unroll
    for (int j = 0; j < 4; ++j) {
      if (EPI == 0) {
        float inv = p0[co + j] * rsqrtf(p3[co + j] + 1e-5f);
        sc[j] = inv; sh[j] = p1[co + j] - p2[co + j] * inv;
      } else if (EPI == 1) {
        sc[j] = 1.f; sh[j] = p0[co + j];
      }
    }
#pragma unroll
    for (int q = 0; q < NR; ++q) {
      int p = p0t + pxw + q * 16 + lr;
      int y = p / W, x = p % W;
      if (EPI == 2) {
#pragma unroll
        for (int j = 0; j < 4; ++j) {
          float v = acc[r][q][j] + p0[(co + j) * 16 + b];
          outf[(((size_t)b * MOUT + co + j) * H + y) * W + x] = v;
        }
      } else {
        ushort_t pk[4];
#pragma unroll
        for (int j = 0; j < 4; ++j) {
          float v = acc[r][q][j] * sc[j] + sh[j];
          if (EPI == 0) v = fmaxf(v, 0.f);
          pk[j] = f2bf(v);
        }
        size_t oidx = OPAD
            ? (((size_t)b * (H + 2) + y + 1) * (W + 2) + x + 1) * MOUT + co
            : (((size_t)b * H + y) * W + x) * MOUT + co;
        *(uint2*)&outb[oidx] = *(const uint2*)pk;
      }
    }
  }
}

__global__ __launch_bounds__(256) void fill_zero(float* __restrict__ p, int n) {
  int i = blockIdx.x * 256 + threadIdx.x;
  if (i < n) p[i] = 0.f;
}

// ---------------------------------------------------------------------------
extern "C" void kernel_launch(void* const* d_in, const int* in_sizes, int n_in,
                              void* d_out, int out_size, void* d_ws, size_t ws_size,
                              hipStream_t stream) {
  (void)in_sizes; (void)n_in;
  const float* x       = (const float*)d_in[0];
  const float* word    = (const float*)d_in[1];
  const float* conv1_w = (const float*)d_in[2];
  const float* bn1_g   = (const float*)d_in[3];
  const float* bn1_b   = (const float*)d_in[4];
  const float* bn1_m   = (const float*)d_in[5];
  const float* bn1_v   = (const float*)d_in[6];
  const float* conv2_w = (const float*)d_in[7];
  const float* bn2_g   = (const float*)d_in[8];
  const float* bn2_b   = (const float*)d_in[9];
  const float* bn2_m   = (const float*)d_in[10];
  const float* bn2_v   = (const float*)d_in[11];
  const float* conv3_w = (const float*)d_in[12];
  const float* conv3_b = (const float*)d_in[13];
  const float* txt_w   = (const float*)d_in[14];
  const float* txt_b   = (const float*)d_in[15];
  float* out = (float*)d_out;

  char* ws = (char*)d_ws;
  size_t off = 0;
  auto alloc = [&](size_t bytes) -> void* {
    void* p = ws + off;
    off += bytes;
    off = (off + 255) & ~(size_t)255;
    return p;
  };
  ushort_t* P0  = (ushort_t*)alloc((size_t)16 * 98 * 98 * 512 * 2);  // 157.35 MB
  ushort_t* up1 = P0;
  ushort_t* up2 = P0;
  ushort_t* vb  = P0;
  ushort_t* a1  = (ushort_t*)alloc((size_t)16 * 48 * 48 * 512 * 2);  // 37.75 MB
  ushort_t* w1b = (ushort_t*)alloc((size_t)512 * 4608 * 2);
  ushort_t* w2b = (ushort_t*)alloc((size_t)256 * 4608 * 2);
  ushort_t* w3b = (ushort_t*)alloc((size_t)256 * 256 * 2);
  ushort_t* wkb = (ushort_t*)alloc((size_t)16 * 128 * 2304 * 2);
  float*    dyb = (float*)alloc((size_t)2048 * 4);
  ushort_t* whi = (ushort_t*)alloc((size_t)2048 * 768 * 2);
  ushort_t* wlo = (ushort_t*)alloc((size_t)2048 * 768 * 2);
  ushort_t* twh = (ushort_t*)alloc((size_t)2432 * 768 * 2);
  ushort_t* twl = (ushort_t*)alloc((size_t)2432 * 768 * 2);
  ushort_t* a2  = (ushort_t*)d_out;  // (16,96,96,256) bf16 == 75,497,472 B exact

  if (ws_size < off) {
    fill_zero<<<(out_size + 255) / 256, 256, 0, stream>>>(out, out_size);
    return;
  }

  // prep
  wprep<<<(512 * 4608 + 255) / 256, 256, 0, stream>>>(conv1_w, w1b, 512, 512, 9);
  wprep<<<(256 * 4608 + 255) / 256, 256, 0, stream>>>(conv2_w, w2b, 256, 512, 9);
  wprep<<<(256 * 256 + 255) / 256, 256, 0, stream>>>(conv3_w, w3b, 256, 256, 1);
  {
    long long nw = (long long)2048 * 768;
    fsplit<<<(int)((nw + 255) / 256), 256, 0, stream>>>(word, whi, wlo, 2048, nw);
    long long nt = (long long)2432 * 768;
    fsplit<<<(int)((nt + 255) / 256), 256, 0, stream>>>(txt_w, twh, twl, 2305, nt);
  }
  text_mfma<<<dim3(19, 16), 256, 0, stream>>>(whi, wlo, twh, twl, txt_b, wkb, dyb);

  // up1 (border + interior)
  {
    long long nbz = (long long)16 * (2 * 50 + 2 * 48) * 512;
    border_zero<<<(int)((nbz + 255) / 256), 256, 0, stream>>>(up1, 16, 50, 50, 512);
    int n = 16 * 48 * 48 * 512;
    upsample1<<<(n + 255) / 256, 256, 0, stream>>>(x, up1);
  }
  // conv1 (8-phase): (16,50,50,512) -> a1 (16,48,48,512)
  conv_mfma8<48, 48, 512, 512>
      <<<dim3(9, 2, 16), 512, 0, stream>>>(up1, w1b, bn1_g, bn1_b, bn1_m, bn1_v, a1);
  // up2 (border + interior)  [P0 reused; up1 dead]
  {
    long long nbz = (long long)16 * (2 * 98 + 2 * 96) * 512;
    border_zero<<<(int)((nbz + 255) / 256), 256, 0, stream>>>(up2, 16, 98, 98, 512);
    int n = 16 * 96 * 96 * 512;
    upsample2<<<(n + 255) / 256, 256, 0, stream>>>(a1, up2);
  }
  // conv2 (8-phase): (16,98,98,512) -> a2 (16,96,96,256) in d_out
  conv_mfma8<96, 96, 512, 256>
      <<<dim3(36, 1, 16), 512, 0, stream>>>(up2, w2b, bn2_g, bn2_b, bn2_m, bn2_v, a2);
  // vb border  [P0 reused; up2 dead]
  {
    long long nbz = (long long)16 * (2 * 98 + 2 * 96) * 256;
    border_zero<<<(int)((nbz + 255) / 256), 256, 0, stream>>>(vb, 16, 98, 98, 256);
  }
  // conv3 1x1: a2 -> vb (16,98,98,256) padded interior
  conv_mfma<1, 1, 256, 128, 2, 2, 96, 96, 256, 256, false, true>
      <<<dim3(72, 1, 16), 256, 0, stream>>>(a2, w3b, conv3_b, nullptr, nullptr, nullptr,
                                            vb, nullptr);
  // dynamic conv: vb -> out (B,128,96,96) f32 NCHW
  conv_mfma<3, 2, 128, 256, 1, 4, 96, 96, 256, 128, true, false>
      <<<dim3(36, 1, 16), 256, 0, stream>>>(vb, wkb, dyb, nullptr, nullptr, nullptr,
                                            nullptr, out);
}